// Round 8
// baseline (166.387 us; speedup 1.0000x reference)
//
#include <hip/hip_runtime.h>
#include <math.h>

// Problem constants (B=4, N=2048, C=81)
#define NPROP 2048
#define NIMG 4
#define NCLS 81
#define REGW 648          // C*8
#define SCORE_THRESH 0.05f
#define NMS_T 0.5f
#define DETS 100
#define XC 1023.0f        // IMG_W - 1
#define YC 799.0f         // IMG_H - 1
#define BBOX_CLIP 4.135166556742356f  // log(1000/16)
#define NBIN 8192         // 13-bit score-bin histogram (v >> 19)
#define SEL 320           // tranche target size
#define MAXC 512          // fast-path candidate cap
#define WRD 8             // MAXC/64 keep words
#define TRI 2304          // triangular matrix words: 64 * (8+7+...+1)
// triangular row-block base: 64 * (8*wb - wb*(wb-1)/2)
#define TB(wb) (64 * (8 * (wb) - ((wb) * ((wb) - 1)) / 2))

typedef unsigned long long u64;

__device__ __forceinline__ float areaf(float4 v) {
  return fmaxf(v.z - v.x + 1.0f, 0.0f) * fmaxf(v.w - v.y + 1.0f, 0.0f);
}
__device__ __forceinline__ bool iou_gt(float4 a, float aa, float4 b, float ba) {
  float ix1 = fmaxf(a.x, b.x), iy1 = fmaxf(a.y, b.y);
  float ix2 = fminf(a.z, b.z), iy2 = fminf(a.w, b.w);
  float iw = fmaxf(ix2 - ix1 + 1.0f, 0.0f);
  float ih = fmaxf(iy2 - iy1 + 1.0f, 0.0f);
  float inter = iw * ih;
  return inter > NMS_T * fmaxf(aa + ba - inter, 1e-6f);
}
__device__ __forceinline__ float score_from_v(unsigned v) {
  unsigned uu = ~v;
  unsigned bits = (uu & 0x80000000u) ? (uu & 0x7fffffffu) : ~uu;
  return __uint_as_float(bits);
}
__device__ __forceinline__ float4 decode_side(const float* __restrict__ reg,
                                              const float4* __restrict__ props,
                                              int grow, int ci, int isR) {
  const float* r = reg + (size_t)grow * REGW + ci * 8 + isR * 4;
  float4 P = props[grow];
  float w  = P.z - P.x + 1.0f;
  float h  = P.w - P.y + 1.0f;
  float cx = P.x + 0.5f * w;
  float cy = P.y + 0.5f * h;
  float dx = r[0] / 10.0f;
  float dy = r[1] / 10.0f;
  float dw = fminf(r[2] / 5.0f, BBOX_CLIP);
  float dh = fminf(r[3] / 5.0f, BBOX_CLIP);
  float pcx = dx * w + cx;
  float pcy = dy * h + cy;
  float pw = expf(dw) * w;
  float ph = expf(dh) * h;
  float4 o;
  o.x = fminf(fmaxf(pcx - 0.5f * pw, 0.0f), XC);
  o.y = fminf(fmaxf(pcy - 0.5f * ph, 0.0f), YC);
  o.z = fminf(fmaxf(pcx + 0.5f * pw - 1.0f, 0.0f), XC);
  o.w = fminf(fmaxf(pcy + 0.5f * ph - 1.0f, 0.0f), YC);
  return o;
}

// ---------------------------------------------------------------------------
// K1: wide per-row softmax-argmax -> v32 (flipped score bits) + ci16.
// ---------------------------------------------------------------------------
__global__ __launch_bounds__(256) void score_kernel(
    const float* __restrict__ logits,
    unsigned* __restrict__ v32G, unsigned short* __restrict__ ci16G) {
  int row  = blockIdx.x * 4 + (threadIdx.x >> 6);
  int lane = threadIdx.x & 63;
  const float* lr = logits + (size_t)row * NCLS;
  float a = lr[lane];
  float b = (lane < NCLS - 64) ? lr[lane + 64] : -INFINITY;
  float v; int ci;
  if (b > a) { v = b; ci = lane + 64; } else { v = a; ci = lane; }
  for (int o = 32; o; o >>= 1) {
    float ov = __shfl_xor(v, o);
    int   oc = __shfl_xor(ci, o);
    if (ov > v || (ov == v && oc < ci)) { v = ov; ci = oc; }
  }
  float e = expf(a - v) + ((lane < NCLS - 64) ? expf(b - v) : 0.0f);
  for (int o = 32; o; o >>= 1) e += __shfl_xor(e, o);
  if (lane == 0) {
    float score = 1.0f / e;
    unsigned vv = 0xFFFFFFFFu;
    if (ci >= 1 && score > SCORE_THRESH) {
      unsigned uu = __float_as_uint(score);
      uu = (uu & 0x80000000u) ? ~uu : (uu | 0x80000000u);
      vv = ~uu;
    }
    v32G[row]  = vv;
    ci16G[row] = (unsigned short)ci;
  }
}

// ---------------------------------------------------------------------------
// K2: per image: 13-bit histogram threshold (SEL), compact, 4-wave rank-sort,
// write sorted (row, v) to global.
// ---------------------------------------------------------------------------
__global__ __launch_bounds__(1024) void select_kernel(
    const unsigned* __restrict__ v32G,
    unsigned short* __restrict__ srowG, unsigned* __restrict__ svG,
    int* __restrict__ C1G, int* __restrict__ C2G, int* __restrict__ flagG) {
  __shared__ int hist[NBIN];          // 32 KB
  __shared__ u64 keys[MAXC];          // 4 KB
  __shared__ int wsum[16];
  __shared__ int Ts, cnts, ovf;
  int b = blockIdx.x, tid = threadIdx.x, ln = tid & 63, w = tid >> 6;
  const unsigned* v32 = v32G + b * NPROP;
  if (tid == 0) { Ts = NBIN - 1; cnts = 0; ovf = 0; }
  for (int i = tid; i < NBIN; i += 1024) hist[i] = 0;
  __syncthreads();
  for (int p = tid; p < NPROP; p += 1024) {
    unsigned v = v32[p];
    if (v != 0xFFFFFFFFu) atomicAdd(&hist[v >> 19], 1);
  }
  __syncthreads();
  {  // scan 8192 bins (8/thread) -> threshold bin Ts (cum >= SEL), total
    int base = tid * 8;
    int c[8]; int acc = 0;
#pragma unroll
    for (int k = 0; k < 8; ++k) { acc += hist[base + k]; c[k] = acc; }
    int tot = acc, v = tot;
#pragma unroll
    for (int o = 1; o < 64; o <<= 1) { int n = __shfl_up(v, o); if (ln >= o) v += n; }
    if (ln == 63) wsum[w] = v;
    __syncthreads();
    if (tid < 16) {
      int x = wsum[tid];
#pragma unroll
      for (int o = 1; o < 16; o <<= 1) { int n = __shfl_up(x, o); if (tid >= o) x += n; }
      wsum[tid] = x;
    }
    __syncthreads();
    int incl = ((w > 0) ? wsum[w - 1] : 0) + v;
    int off = incl - tot;
    int prev = off;
#pragma unroll
    for (int k = 0; k < 8; ++k) {
      int cur = off + c[k];
      if (cur >= SEL && prev < SEL) Ts = base + k;
      prev = cur;
    }
  }
  __syncthreads();
  int T = Ts, nvTot = wsum[15];
  for (int p = tid; p < NPROP; p += 1024) {   // compact bin <= T
    unsigned v = v32[p];
    bool cand = (v != 0xFFFFFFFFu) && ((int)(v >> 19) <= T);
    u64 mb = __ballot(cand);
    int lpos = (int)__popcll(mb & ((1ull << ln) - 1ull));
    int wb = 0;
    if (ln == 0 && mb) wb = atomicAdd(&cnts, (int)__popcll(mb));
    wb = __shfl(wb, 0);
    if (cand) {
      int dst = wb + lpos;
      if (dst < MAXC) keys[dst] = ((u64)v << 16) | (unsigned)p;
      else ovf = 1;
    }
  }
  __syncthreads();
  int C1 = cnts;
  if (C1 > MAXC || ovf) {
    if (tid == 0) { flagG[b] = 1; C1G[b] = 0; C2G[b] = nvTot; }
    return;
  }
  if (tid < 256) {   // rank-sort, 2 keys/thread (4 waves issue LDS loop)
    int i0 = tid, i1 = tid + 256;
    u64 k0 = (i0 < C1) ? keys[i0] : ~0ull;
    u64 k1 = (i1 < C1) ? keys[i1] : ~0ull;
    int r0 = 0, r1 = 0;
#pragma unroll 4
    for (int j = 0; j < C1; ++j) {
      u64 kj = keys[j];
      r0 += (kj < k0) ? 1 : 0;
      r1 += (kj < k1) ? 1 : 0;
    }
    if (i0 < C1) { srowG[b * MAXC + r0] = (unsigned short)(k0 & 0xFFFFull);
                   svG[b * MAXC + r0]   = (unsigned)(k0 >> 16); }
    if (i1 < C1) { srowG[b * MAXC + r1] = (unsigned short)(k1 & 0xFFFFull);
                   svG[b * MAXC + r1]   = (unsigned)(k1 >> 16); }
  }
  if (tid == 0) { flagG[b] = 0; C1G[b] = C1; C2G[b] = nvTot; }
}

// ---------------------------------------------------------------------------
// K3 (wide, 72x256): zero output + decode selected boxes to global.
// ---------------------------------------------------------------------------
__global__ __launch_bounds__(256) void prep_kernel(
    const float* __restrict__ reg, const float* __restrict__ lp,
    const float* __restrict__ rp, const unsigned short* __restrict__ ci16G,
    const unsigned short* __restrict__ srowG, const int* __restrict__ C1G,
    const int* __restrict__ flagG, float* __restrict__ out,
    float4* __restrict__ bxLG, float4* __restrict__ bxRG) {
  int g = blockIdx.x * 256 + threadIdx.x;       // 0..18431
  float4 z4 = make_float4(0.f, 0.f, 0.f, 0.f);
  ((float4*)out)[g] = z4;                       // 4*2048*9/4 = 18432 exactly
  if (g < NIMG * MAXC) {
    int b = g >> 9, pos = g & (MAXC - 1);
    float4 L = z4, R = z4;
    if (flagG[b] == 0 && pos < C1G[b]) {
      int row  = srowG[b * MAXC + pos];
      int grow = b * NPROP + row;
      int ci   = ci16G[grow];
      L = decode_side(reg, (const float4*)lp, grow, ci, 0);
      R = decode_side(reg, (const float4*)rp, grow, ci, 1);
    }
    bxLG[g] = L; bxRG[g] = R;
  }
}

// ---------------------------------------------------------------------------
// K4 (8 blocks = image x side): build triangular IoU bit matrix in LDS via
// row-per-lane register accumulation (no shuffles/ballots), then branchless
// lane-0 serial greedy; write keep words (<=8 u64) to global.
// ---------------------------------------------------------------------------
__global__ __launch_bounds__(1024) void build_kernel(
    const float4* __restrict__ bxLG, const float4* __restrict__ bxRG,
    const int* __restrict__ C1G, const int* __restrict__ flagG,
    u64* __restrict__ keepLG, u64* __restrict__ keepRG) {
  __shared__ float4 bx[MAXC];     // 8 KB
  __shared__ float  ar[MAXC];     // 2 KB
  __shared__ u64    mat[TRI];     // 18.4 KB
  __shared__ int C1_s, flag_s;
  int b = blockIdx.x >> 1, side = blockIdx.x & 1;
  int tid = threadIdx.x, ln = tid & 63, w = tid >> 6;
  if (tid == 0) { C1_s = C1G[b]; flag_s = flagG[b]; }
  __syncthreads();
  if (flag_s) return;
  int C1 = C1_s;
  if (C1 == 0) return;
  const float4* src = (side ? bxRG : bxLG) + b * MAXC;
  for (int i = tid; i < MAXC; i += 1024) {
    float4 f = src[i];
    bx[i] = f; ar[i] = areaf(f);
  }
  __syncthreads();
  int WRDu = (C1 + 63) >> 6;
  int rb = w & 7, part = w >> 3;        // row-block, column partner (0/1)
  int r = rb * 64 + ln;
  float4 rbx = bx[r];
  float  rar = ar[r];
  int tbase = TB(rb) + ln * (8 - rb);
  for (int cw = rb + part; cw < WRDu; cw += 2) {
    u64 m = 0;
#pragma unroll 4
    for (int c = 0; c < 64; ++c) {
      int col = cw * 64 + c;
      float4 cb = bx[col];              // same-address broadcast ds_read_b128
      float car = areaf(cb);            // recompute in VALU (DS is the scarce pipe)
      bool bit = (col > r) && (col < C1) && iou_gt(rbx, rar, cb, car);
      m |= ((u64)bit) << c;
    }
    mat[tbase + (cw - rb)] = m;
  }
  __syncthreads();
  if (tid == 0) {
    u64 A[WRD];
#pragma unroll
    for (int t = 0; t < WRD; ++t) {
      int b0 = t * 64;
      A[t] = (C1 >= b0 + 64) ? ~0ull : (C1 > b0 ? ((1ull << (C1 - b0)) - 1ull) : 0ull);
    }
#pragma unroll
    for (int wb = 0; wb < WRD; ++wb) {
      if (wb * 64 >= C1) break;
      u64 aw = A[wb];
      const u64* rp0 = &mat[TB(wb)];
      const int W = 8 - wb;
      for (int l = 0; l < 64; ++l) {
        int j = wb * 64 + l;
        if (j >= C1) break;
        u64 msk = 0ull - ((aw >> l) & 1ull);
        const u64* rp = rp0 + l * W;    // unconditional loads: prefetchable
        aw &= ~(msk & rp[0]);
#pragma unroll
        for (int t = wb + 1; t < WRD; ++t) A[t] &= ~(msk & rp[t - wb]);
      }
      A[wb] = aw;
    }
    u64* kG = (side ? keepRG : keepLG) + b * WRD;
    for (int t = 0; t < WRDu; ++t) kG[t] = A[t];
  }
}

// ---------------------------------------------------------------------------
// K5 (4 blocks x 64): AND keeps, rank, kth tie handling, write output rows;
// set fallback flag if <100 survivors while candidates remain beyond C1.
// ---------------------------------------------------------------------------
__global__ __launch_bounds__(64) void finale_kernel(
    const u64* __restrict__ keepLG, const u64* __restrict__ keepRG,
    const unsigned* __restrict__ svG, const unsigned short* __restrict__ srowG,
    const float4* __restrict__ bxLG, const float4* __restrict__ bxRG,
    const int* __restrict__ C1G, const int* __restrict__ C2G,
    int* __restrict__ flagG, float* __restrict__ out) {
  int b = blockIdx.x, ln = threadIdx.x;
  if (flagG[b]) return;
  int C1 = C1G[b];
  int WRDu = (C1 + 63) >> 6;
  int before = 0;
  unsigned kth = 0;
  float* ob = out + (size_t)b * NPROP * 9;
  for (int wb = 0; wb < WRDu; ++wb) {
    u64 m = keepLG[b * WRD + wb] & keepRG[b * WRD + wb];
    int pos = wb * 64 + ln;
    bool bit = (m >> ln) & 1ull;
    int rank = before + (int)__popcll(m & ((1ull << ln) - 1ull));
    unsigned vA = svG[b * MAXC + pos];
    u64 selm = __ballot(bit && rank == DETS - 1);
    if (selm) kth = __shfl(vA, __ffsll(selm) - 1);
    bool qual = bit && (rank < DETS || vA == kth);
    if (qual) {
      int row = srowG[b * MAXC + pos];
      float4 L = bxLG[b * MAXC + pos], R = bxRG[b * MAXC + pos];
      float* orow = ob + row * 9;
      orow[0]=L.x; orow[1]=L.y; orow[2]=L.z; orow[3]=L.w;
      orow[4]=R.x; orow[5]=R.y; orow[6]=R.z; orow[7]=R.w;
      orow[8]=score_from_v(vA);
    }
    before += (int)__popcll(m);
  }
  if (ln == 0 && before < DETS && C2G[b] > C1) flagG[b] = 1;
}

// ---------------------------------------------------------------------------
// K6: dormant exact fallback (R6/R7's verified full-scope kernel, flag-gated).
// ---------------------------------------------------------------------------
struct SN {
  u64 keys[NPROP];
  unsigned short sidx[NPROP];
  unsigned v32s[NPROP];
  float4 bxL[MAXC], bxR[MAXC];
  float  arL[MAXC], arR[MAXC];
  u64 keepbL[NPROP / 64], keepbR[NPROP / 64];
  u64 rowmL[64], rowmR[64];
  float4 cbL[64], cbR[64];
  float  cbLa[64], cbRa[64];
  u64 aL, aR;
  int cnt, prevCount, done, ccL, ccR, flag_s;
  unsigned kthV;
};

__device__ __forceinline__ float4 get_sboxN(SN* S, const float* reg,
                                            const float4* lp4, const float4* rp4,
                                            const unsigned short* ci16G,
                                            int b, int pos, int isR) {
  if (pos < MAXC) return isR ? S->bxR[pos] : S->bxL[pos];
  int row = S->sidx[pos];
  int grow = b * NPROP + row;
  return decode_side(reg, isR ? rp4 : lp4, grow, ci16G[grow], isR);
}

__global__ __launch_bounds__(1024) void fallback_kernel(
    const float* __restrict__ reg, const float* __restrict__ lp,
    const float* __restrict__ rp, const unsigned* __restrict__ v32G,
    const unsigned short* __restrict__ ci16G, const int* __restrict__ flagG,
    float* __restrict__ out) {
  __shared__ SN S;
  int b = blockIdx.x, tid = threadIdx.x, ln = tid & 63, w = tid >> 6;
  if (tid == 0) { S.flag_s = flagG[b]; S.cnt = 0; S.prevCount = 0; S.done = 0; S.kthV = 0u; }
  __syncthreads();
  if (!S.flag_s) return;
  const float4* lp4 = (const float4*)lp;
  const float4* rp4 = (const float4*)rp;
  float* ob = out + (size_t)b * NPROP * 9;
  float4* ob4 = (float4*)ob;
  float4 z4 = make_float4(0.f, 0.f, 0.f, 0.f);
  for (int i = tid; i < NPROP * 9 / 4; i += 1024) ob4[i] = z4;
  for (int p = tid; p < NPROP; p += 1024) {
    unsigned v = v32G[b * NPROP + p];
    S.v32s[p] = v;
    bool cand = (v != 0xFFFFFFFFu);
    u64 mb = __ballot(cand);
    int lpos = (int)__popcll(mb & ((1ull << ln) - 1ull));
    int wb = 0;
    if (ln == 0 && mb) wb = atomicAdd(&S.cnt, (int)__popcll(mb));
    wb = __shfl(wb, 0);
    if (cand) S.keys[wb + lpos] = ((u64)v << 16) | (unsigned)p;
  }
  __syncthreads();
  int C2 = S.cnt;
  int CbEnd = (C2 + 63) & ~63;
  {
    int i0 = tid, i1 = tid + 1024;
    u64 k0 = (i0 < C2) ? S.keys[i0] : ~0ull;
    u64 k1 = (i1 < C2) ? S.keys[i1] : ~0ull;
    int r0 = 0, r1 = 0;
#pragma unroll 4
    for (int j = 0; j < C2; ++j) {
      u64 kj = S.keys[j];
      r0 += (kj < k0) ? 1 : 0;
      r1 += (kj < k1) ? 1 : 0;
    }
    if (i0 < C2) S.sidx[r0] = (unsigned short)(k0 & 0xFFFFull);
    if (i1 < C2) S.sidx[r1] = (unsigned short)(k1 & 0xFFFFull);
  }
  for (int i = C2 + tid; i < CbEnd; i += 1024) S.sidx[i] = 0;
  for (int wd = tid; wd < NPROP / 64; wd += 1024) {
    int b0 = wd << 6;
    u64 mf = 0ull;
    if (C2 >= b0 + 64) mf = ~0ull;
    else if (C2 > b0)  mf = (1ull << (C2 - b0)) - 1ull;
    S.keepbL[wd] = mf; S.keepbR[wd] = mf;
  }
  __syncthreads();
  {
    int lim = min(CbEnd, MAXC);
    for (int i = tid; i < lim; i += 1024) {
      if (i < C2) {
        int row = S.sidx[i];
        int grow = b * NPROP + row;
        int ci = ci16G[grow];
        float4 L = decode_side(reg, lp4, grow, ci, 0);
        float4 R = decode_side(reg, rp4, grow, ci, 1);
        S.bxL[i] = L; S.arL[i] = areaf(L);
        S.bxR[i] = R; S.arR[i] = areaf(R);
      } else {
        S.bxL[i] = z4; S.arL[i] = 1.0f;
        S.bxR[i] = z4; S.arR[i] = 1.0f;
      }
    }
  }
  __syncthreads();
  for (int base = 0; base < CbEnd; base += 64) {
    {
      int isR = (w >= 8);
      float4 cbx = get_sboxN(&S, reg, lp4, rp4, ci16G, b, base + ln, isR);
      float car = (base + ln < MAXC) ? (isR ? S.arR[base + ln] : S.arL[base + ln])
                                     : areaf(cbx);
      int w8 = w & 7;
#pragma unroll
      for (int k = 0; k < 8; ++k) {
        int row = w8 * 8 + k;
        float4 rbx;
        rbx.x = __shfl(cbx.x, row); rbx.y = __shfl(cbx.y, row);
        rbx.z = __shfl(cbx.z, row); rbx.w = __shfl(cbx.w, row);
        float rar = __shfl(car, row);
        bool bit = (ln > row) && iou_gt(rbx, rar, cbx, car);
        u64 bal = __ballot(bit);
        if (ln == 0) { if (isR) S.rowmR[row] = bal; else S.rowmL[row] = bal; }
      }
    }
    __syncthreads();
    if (tid < 128) {
      int isR = (tid >= 64);
      u64* km = isR ? S.keepbR : S.keepbL;
      u64* rm = isR ? S.rowmR  : S.rowmL;
      u64 a = km[base >> 6];
#pragma unroll
      for (int j = 0; j < 64; ++j)
        a &= ~((0ull - ((a >> j) & 1ull)) & rm[j]);
      if (ln == 0) {
        km[base >> 6] = a;
        if (isR) { S.aR = a; S.ccR = __popcll(a); }
        else     { S.aL = a; S.ccL = __popcll(a); }
      }
      if ((a >> ln) & 1ull) {
        int pos = __popcll(a & ((1ull << ln) - 1ull));
        float4 v = get_sboxN(&S, reg, lp4, rp4, ci16G, b, base + ln, isR);
        if (isR) { S.cbR[pos] = v; S.cbRa[pos] = areaf(v); }
        else     { S.cbL[pos] = v; S.cbLa[pos] = areaf(v); }
      }
    }
    __syncthreads();
    if (w == 0) {
      u64 m = S.aL & S.aR;
      int before = S.prevCount;
      bool bit = (m >> ln) & 1ull;
      int rank = before + (int)__popcll(m & ((1ull << ln) - 1ull));
      int row = S.sidx[base + ln];
      unsigned vA = S.v32s[row];
      u64 selm = __ballot(bit && rank == DETS - 1);
      unsigned keffV = S.kthV;
      if (selm) keffV = __shfl(vA, __ffsll(selm) - 1);
      bool qual = bit && (rank < DETS || vA == keffV);
      if (qual) {
        float4 L = get_sboxN(&S, reg, lp4, rp4, ci16G, b, base + ln, 0);
        float4 R = get_sboxN(&S, reg, lp4, rp4, ci16G, b, base + ln, 1);
        float s = score_from_v(vA);
        float* orow = ob + row * 9;
        orow[0]=L.x; orow[1]=L.y; orow[2]=L.z; orow[3]=L.w;
        orow[4]=R.x; orow[5]=R.y; orow[6]=R.z; orow[7]=R.w;
        orow[8]=s;
      }
      if (ln == 0) {
        if (selm) S.kthV = keffV;
        int nc = before + (int)__popcll(m);
        S.prevCount = nc;
        if (nc >= DETS) {
          int nxt = base + 64;
          bool cont = false;
          if (nxt < C2) cont = (S.v32s[S.sidx[nxt]] == keffV);
          if (!cont) S.done = 1;
        }
      }
    } else {
      int cL = S.ccL, cR = S.ccR;
      if ((cL | cR) != 0) {
        for (int p = base + 64 + (tid - 64); p < CbEnd; p += 960) {
          float4 mbL = get_sboxN(&S, reg, lp4, rp4, ci16G, b, p, 0);
          float al = (p < MAXC) ? S.arL[p] : areaf(mbL);
          bool supL = false;
          for (int q = 0; q < cL; ++q)
            supL = supL || iou_gt(mbL, al, S.cbL[q], S.cbLa[q]);
          if (supL) atomicAnd(&S.keepbL[p >> 6], ~(1ull << (p & 63)));
          float4 mbR = get_sboxN(&S, reg, lp4, rp4, ci16G, b, p, 1);
          float ar_ = (p < MAXC) ? S.arR[p] : areaf(mbR);
          bool supR = false;
          for (int q = 0; q < cR; ++q)
            supR = supR || iou_gt(mbR, ar_, S.cbR[q], S.cbRa[q]);
          if (supR) atomicAnd(&S.keepbR[p >> 6], ~(1ull << (p & 63)));
        }
      }
    }
    __syncthreads();
    if (S.done) break;
  }
}

// ---------------------------------------------------------------------------
extern "C" void kernel_launch(void* const* d_in, const int* in_sizes, int n_in,
                              void* d_out, int out_size, void* d_ws, size_t ws_size,
                              hipStream_t stream) {
  const float* logits = (const float*)d_in[0];   // [8192, 81]
  const float* reg    = (const float*)d_in[1];   // [8192, 648]
  const float* lprop  = (const float*)d_in[2];   // [8192, 4]
  const float* rprop  = (const float*)d_in[3];   // [8192, 4]
  float* out = (float*)d_out;                    // [4, 2048, 9]

  char* ws = (char*)d_ws;                        // ~125 KB used
  unsigned*       v32G   = (unsigned*)(ws + 0);          // 32 KB
  unsigned short* ci16G  = (unsigned short*)(ws + 32768);// 16 KB
  unsigned short* srowG  = (unsigned short*)(ws + 49152);// 4 KB
  unsigned*       svG    = (unsigned*)(ws + 53248);      // 8 KB
  float4*         bxLG   = (float4*)(ws + 61440);        // 32 KB
  float4*         bxRG   = (float4*)(ws + 94208);        // 32 KB
  u64*            keepLG = (u64*)(ws + 126976);          // 256 B
  u64*            keepRG = (u64*)(ws + 127232);          // 256 B
  int*            C1G    = (int*)(ws + 127488);
  int*            C2G    = (int*)(ws + 127504);
  int*            flagG  = (int*)(ws + 127520);

  score_kernel   <<<NIMG * NPROP / 4, 256,  0, stream>>>(logits, v32G, ci16G);
  select_kernel  <<<NIMG,             1024, 0, stream>>>(v32G, srowG, svG, C1G, C2G, flagG);
  prep_kernel    <<<72,               256,  0, stream>>>(reg, lprop, rprop, ci16G, srowG,
                                                         C1G, flagG, out, bxLG, bxRG);
  build_kernel   <<<2 * NIMG,         1024, 0, stream>>>(bxLG, bxRG, C1G, flagG,
                                                         keepLG, keepRG);
  finale_kernel  <<<NIMG,             64,   0, stream>>>(keepLG, keepRG, svG, srowG,
                                                         bxLG, bxRG, C1G, C2G, flagG, out);
  fallback_kernel<<<NIMG,             1024, 0, stream>>>(reg, lprop, rprop, v32G, ci16G,
                                                         flagG, out);
}

// Round 9
// 129.557 us; speedup vs baseline: 1.2843x; 1.2843x over previous
//
#include <hip/hip_runtime.h>
#include <math.h>

// Problem constants (B=4, N=2048, C=81)
#define NPROP 2048
#define NIMG 4
#define NCLS 81
#define REGW 648          // C*8
#define SCORE_THRESH 0.05f
#define NMS_T 0.5f
#define DETS 100
#define XC 1023.0f        // IMG_W - 1
#define YC 799.0f         // IMG_H - 1
#define BBOX_CLIP 4.135166556742356f  // log(1000/16)
#define NBIN 8192         // 13-bit score-bin histogram (v >> 19)
#define SEL 320           // tranche target size
#define MAXC 512          // fast-path candidate cap
#define WRD 8             // MAXC/64 keep words
#define TRIP 2560         // padded triangular words: 64*(9+7+7+5+5+3+3+1)

typedef unsigned long long u64;

__device__ __forceinline__ float areaf(float4 v) {
  return fmaxf(v.z - v.x + 1.0f, 0.0f) * fmaxf(v.w - v.y + 1.0f, 0.0f);
}
__device__ __forceinline__ bool iou_gt(float4 a, float aa, float4 b, float ba) {
  float ix1 = fmaxf(a.x, b.x), iy1 = fmaxf(a.y, b.y);
  float ix2 = fminf(a.z, b.z), iy2 = fminf(a.w, b.w);
  float iw = fmaxf(ix2 - ix1 + 1.0f, 0.0f);
  float ih = fmaxf(iy2 - iy1 + 1.0f, 0.0f);
  float inter = iw * ih;
  return inter > NMS_T * fmaxf(aa + ba - inter, 1e-6f);
}
__device__ __forceinline__ float score_from_v(unsigned v) {
  unsigned uu = ~v;
  unsigned bits = (uu & 0x80000000u) ? (uu & 0x7fffffffu) : ~uu;
  return __uint_as_float(bits);
}
__device__ __forceinline__ float4 decode_side(const float* __restrict__ reg,
                                              const float4* __restrict__ props,
                                              int grow, int ci, int isR) {
  const float* r = reg + (size_t)grow * REGW + ci * 8 + isR * 4;
  float4 P = props[grow];
  float w  = P.z - P.x + 1.0f;
  float h  = P.w - P.y + 1.0f;
  float cx = P.x + 0.5f * w;
  float cy = P.y + 0.5f * h;
  float dx = r[0] / 10.0f;
  float dy = r[1] / 10.0f;
  float dw = fminf(r[2] / 5.0f, BBOX_CLIP);
  float dh = fminf(r[3] / 5.0f, BBOX_CLIP);
  float pcx = dx * w + cx;
  float pcy = dy * h + cy;
  float pw = expf(dw) * w;
  float ph = expf(dh) * h;
  float4 o;
  o.x = fminf(fmaxf(pcx - 0.5f * pw, 0.0f), XC);
  o.y = fminf(fmaxf(pcy - 0.5f * ph, 0.0f), YC);
  o.z = fminf(fmaxf(pcx + 0.5f * pw - 1.0f, 0.0f), XC);
  o.w = fminf(fmaxf(pcy + 0.5f * ph - 1.0f, 0.0f), YC);
  return o;
}

// ---------------------------------------------------------------------------
// K1: wide per-row softmax-argmax -> v32 (flipped score bits) + ci16.
// ---------------------------------------------------------------------------
__global__ __launch_bounds__(256) void score_kernel(
    const float* __restrict__ logits,
    unsigned* __restrict__ v32G, unsigned short* __restrict__ ci16G) {
  int row  = blockIdx.x * 4 + (threadIdx.x >> 6);
  int lane = threadIdx.x & 63;
  const float* lr = logits + (size_t)row * NCLS;
  float a = lr[lane];
  float b = (lane < NCLS - 64) ? lr[lane + 64] : -INFINITY;
  float v; int ci;
  if (b > a) { v = b; ci = lane + 64; } else { v = a; ci = lane; }
  for (int o = 32; o; o >>= 1) {
    float ov = __shfl_xor(v, o);
    int   oc = __shfl_xor(ci, o);
    if (ov > v || (ov == v && oc < ci)) { v = ov; ci = oc; }
  }
  float e = expf(a - v) + ((lane < NCLS - 64) ? expf(b - v) : 0.0f);
  for (int o = 32; o; o >>= 1) e += __shfl_xor(e, o);
  if (lane == 0) {
    float score = 1.0f / e;
    unsigned vv = 0xFFFFFFFFu;
    if (ci >= 1 && score > SCORE_THRESH) {
      unsigned uu = __float_as_uint(score);
      uu = (uu & 0x80000000u) ? ~uu : (uu | 0x80000000u);
      vv = ~uu;
    }
    v32G[row]  = vv;
    ci16G[row] = (unsigned short)ci;
  }
}

// ---------------------------------------------------------------------------
// K2: per image: 13-bit histogram threshold (SEL), compact, 4-wave rank-sort.
// ---------------------------------------------------------------------------
__global__ __launch_bounds__(1024) void select_kernel(
    const unsigned* __restrict__ v32G,
    unsigned short* __restrict__ srowG, unsigned* __restrict__ svG,
    int* __restrict__ C1G, int* __restrict__ C2G, int* __restrict__ flagG) {
  __shared__ int hist[NBIN];          // 32 KB
  __shared__ u64 keys[MAXC];          // 4 KB
  __shared__ int wsum[16];
  __shared__ int Ts, cnts, ovf;
  int b = blockIdx.x, tid = threadIdx.x, ln = tid & 63, w = tid >> 6;
  const unsigned* v32 = v32G + b * NPROP;
  if (tid == 0) { Ts = NBIN - 1; cnts = 0; ovf = 0; }
  for (int i = tid; i < NBIN; i += 1024) hist[i] = 0;
  __syncthreads();
  for (int p = tid; p < NPROP; p += 1024) {
    unsigned v = v32[p];
    if (v != 0xFFFFFFFFu) atomicAdd(&hist[v >> 19], 1);
  }
  __syncthreads();
  {  // scan 8192 bins (8/thread) -> threshold bin Ts (cum >= SEL), total
    int base = tid * 8;
    int c[8]; int acc = 0;
#pragma unroll
    for (int k = 0; k < 8; ++k) { acc += hist[base + k]; c[k] = acc; }
    int tot = acc, v = tot;
#pragma unroll
    for (int o = 1; o < 64; o <<= 1) { int n = __shfl_up(v, o); if (ln >= o) v += n; }
    if (ln == 63) wsum[w] = v;
    __syncthreads();
    if (tid < 16) {
      int x = wsum[tid];
#pragma unroll
      for (int o = 1; o < 16; o <<= 1) { int n = __shfl_up(x, o); if (tid >= o) x += n; }
      wsum[tid] = x;
    }
    __syncthreads();
    int incl = ((w > 0) ? wsum[w - 1] : 0) + v;
    int off = incl - tot;
    int prev = off;
#pragma unroll
    for (int k = 0; k < 8; ++k) {
      int cur = off + c[k];
      if (cur >= SEL && prev < SEL) Ts = base + k;
      prev = cur;
    }
  }
  __syncthreads();
  int T = Ts, nvTot = wsum[15];
  for (int p = tid; p < NPROP; p += 1024) {   // compact bin <= T
    unsigned v = v32[p];
    bool cand = (v != 0xFFFFFFFFu) && ((int)(v >> 19) <= T);
    u64 mb = __ballot(cand);
    int lpos = (int)__popcll(mb & ((1ull << ln) - 1ull));
    int wb = 0;
    if (ln == 0 && mb) wb = atomicAdd(&cnts, (int)__popcll(mb));
    wb = __shfl(wb, 0);
    if (cand) {
      int dst = wb + lpos;
      if (dst < MAXC) keys[dst] = ((u64)v << 16) | (unsigned)p;
      else ovf = 1;
    }
  }
  __syncthreads();
  int C1 = cnts;
  if (C1 > MAXC || ovf) {
    if (tid == 0) { flagG[b] = 1; C1G[b] = 0; C2G[b] = nvTot; }
    return;
  }
  if (tid < 256) {   // rank-sort, 2 keys/thread (4 waves issue the LDS loop)
    int i0 = tid, i1 = tid + 256;
    u64 k0 = (i0 < C1) ? keys[i0] : ~0ull;
    u64 k1 = (i1 < C1) ? keys[i1] : ~0ull;
    int r0 = 0, r1 = 0;
#pragma unroll 4
    for (int j = 0; j < C1; ++j) {
      u64 kj = keys[j];
      r0 += (kj < k0) ? 1 : 0;
      r1 += (kj < k1) ? 1 : 0;
    }
    if (i0 < C1) { srowG[b * MAXC + r0] = (unsigned short)(k0 & 0xFFFFull);
                   svG[b * MAXC + r0]   = (unsigned)(k0 >> 16); }
    if (i1 < C1) { srowG[b * MAXC + r1] = (unsigned short)(k1 & 0xFFFFull);
                   svG[b * MAXC + r1]   = (unsigned)(k1 >> 16); }
  }
  if (tid == 0) { flagG[b] = 0; C1G[b] = C1; C2G[b] = nvTot; }
}

// ---------------------------------------------------------------------------
// K3 (wide, 72x256): zero output + decode selected boxes to global (pads=0).
// ---------------------------------------------------------------------------
__global__ __launch_bounds__(256) void prep_kernel(
    const float* __restrict__ reg, const float* __restrict__ lp,
    const float* __restrict__ rp, const unsigned short* __restrict__ ci16G,
    const unsigned short* __restrict__ srowG, const int* __restrict__ C1G,
    const int* __restrict__ flagG, float* __restrict__ out,
    float4* __restrict__ bxLG, float4* __restrict__ bxRG) {
  int g = blockIdx.x * 256 + threadIdx.x;       // 0..18431
  float4 z4 = make_float4(0.f, 0.f, 0.f, 0.f);
  ((float4*)out)[g] = z4;                       // 4*2048*9/4 = 18432 exactly
  if (g < NIMG * MAXC) {
    int b = g >> 9, pos = g & (MAXC - 1);
    float4 L = z4, R = z4;
    if (flagG[b] == 0 && pos < C1G[b]) {
      int row  = srowG[b * MAXC + pos];
      int grow = b * NPROP + row;
      int ci   = ci16G[grow];
      L = decode_side(reg, (const float4*)lp, grow, ci, 0);
      R = decode_side(reg, (const float4*)rp, grow, ci, 1);
    }
    bxLG[g] = L; bxRG[g] = R;
  }
}

// ---------------------------------------------------------------------------
// K4 (8 blocks = image x side): triangular IoU bit matrix (row-per-lane,
// odd strides, no per-iter bound checks), then a latency-free greedy:
// per 64-row block, diag-only serial sweep with register-batched prefetch
// (all 64 lanes redundant, broadcast reads), then lane-parallel off-diagonal
// suppression via shfl_xor OR-reduce. A lives in registers; no barriers.
// ---------------------------------------------------------------------------
__global__ __launch_bounds__(1024) void build_kernel(
    const float4* __restrict__ bxLG, const float4* __restrict__ bxRG,
    const int* __restrict__ C1G, const int* __restrict__ flagG,
    u64* __restrict__ keepLG, u64* __restrict__ keepRG) {
  __shared__ float4 bx[MAXC];     // 8 KB
  __shared__ u64    mat[TRIP];    // 20 KB, row-block-major, stride (8-wb)|1
  __shared__ int C1_s, flag_s;
  int b = blockIdx.x >> 1, side = blockIdx.x & 1;
  int tid = threadIdx.x, ln = tid & 63, w = tid >> 6;
  if (tid == 0) { C1_s = C1G[b]; flag_s = flagG[b]; }
  __syncthreads();
  if (flag_s) return;
  int C1 = C1_s;
  if (C1 == 0) return;
  int WRDu = (C1 + 63) >> 6;
  const float4* src = (side ? bxRG : bxLG) + b * MAXC;
  if (tid < MAXC) bx[tid] = src[tid];
  __syncthreads();

  // ---- matrix build: wave w -> row-block rb=w&7, column parity part=w>>3 ----
  {
    int rb = w & 7, part = w >> 3;
    int r = rb * 64 + ln;
    float4 rbx = bx[r];
    float  rar = areaf(rbx);
    int tb = 0;
    for (int k = 0; k < rb; ++k) tb += ((8 - k) | 1);
    int Sw = (8 - rb) | 1;
    u64* myrow = &mat[tb * 64 + ln * Sw];
    for (int cw = rb + part; cw < WRDu; cw += 2) {
      u64 m = 0;
      const float4* cp = &bx[cw * 64];
#pragma unroll 8
      for (int c = 0; c < 64; ++c) {
        float4 cb = cp[c];             // same-address broadcast ds_read_b128
        float car = areaf(cb);
        if (iou_gt(rbx, rar, cb, car)) m |= (1ull << c);
      }
      if (cw == rb) m &= ~((2ull << ln) - 1ull);   // keep only col > r
      myrow[cw - rb] = m;
    }
  }
  __syncthreads();

  // ---- greedy: wave 0, all lanes redundant, zero barriers ----
  if (w == 0) {
    u64 A[WRD];
#pragma unroll
    for (int t = 0; t < WRD; ++t) {
      int b0 = t * 64;
      A[t] = (C1 >= b0 + 64) ? ~0ull : (C1 > b0 ? ((1ull << (C1 - b0)) - 1ull) : 0ull);
    }
    int tbase = 0;
#pragma unroll
    for (int wb = 0; wb < WRD; ++wb) {
      if (wb * 64 < C1) {
        const int Sw = (8 - wb) | 1;
        const u64* rowp = &mat[tbase];
        u64 aw = A[wb];
        // diag-only serial sweep; loads batched 16-at-a-time into registers
#pragma unroll
        for (int g = 0; g < 4; ++g) {
          u64 d[16];
#pragma unroll
          for (int k = 0; k < 16; ++k) d[k] = rowp[(g * 16 + k) * Sw];
#pragma unroll
          for (int k = 0; k < 16; ++k) {
            u64 msk = 0ull - ((aw >> (g * 16 + k)) & 1ull);
            aw &= ~(msk & d[k]);
          }
        }
        A[wb] = aw;
        // off-diagonal suppression: lane-parallel, shfl OR-reduce
        bool alive = (aw >> ln) & 1ull;
#pragma unroll
        for (int t = wb + 1; t < WRD; ++t) {
          if (t * 64 < C1) {
            u64 x = alive ? rowp[ln * Sw + (t - wb)] : 0ull;
#pragma unroll
            for (int o = 1; o < 64; o <<= 1)
              x |= __shfl_xor((unsigned long long)x, o);
            A[t] &= ~x;
          }
        }
      }
      tbase += 64 * ((8 - wb) | 1);
    }
    if (ln == 0) {
      u64* kG = (side ? keepRG : keepLG) + b * WRD;
#pragma unroll
      for (int t = 0; t < WRD; ++t)
        if (t * 64 < C1) kG[t] = A[t];
    }
  }
}

// ---------------------------------------------------------------------------
// K5: finale (wave 0) + dormant exact fallback in one kernel (4 blocks).
// ---------------------------------------------------------------------------
struct SN {
  u64 keys[NPROP];
  unsigned short sidx[NPROP];
  unsigned v32s[NPROP];
  float4 bxL[MAXC], bxR[MAXC];
  float  arL[MAXC], arR[MAXC];
  u64 keepbL[NPROP / 64], keepbR[NPROP / 64];
  u64 rowmL[64], rowmR[64];
  float4 cbL[64], cbR[64];
  float  cbLa[64], cbRa[64];
  u64 aL, aR;
  int cnt, prevCount, done, ccL, ccR, needFB;
  unsigned kthV;
};

__device__ __forceinline__ float4 get_sboxN(SN* S, const float* reg,
                                            const float4* lp4, const float4* rp4,
                                            const unsigned short* ci16G,
                                            int b, int pos, int isR) {
  if (pos < MAXC) return isR ? S->bxR[pos] : S->bxL[pos];
  int row = S->sidx[pos];
  int grow = b * NPROP + row;
  return decode_side(reg, isR ? rp4 : lp4, grow, ci16G[grow], isR);
}

__global__ __launch_bounds__(1024) void finale_fallback_kernel(
    const float* __restrict__ reg, const float* __restrict__ lp,
    const float* __restrict__ rp, const unsigned* __restrict__ v32G,
    const unsigned short* __restrict__ ci16G,
    const u64* __restrict__ keepLG, const u64* __restrict__ keepRG,
    const unsigned* __restrict__ svG, const unsigned short* __restrict__ srowG,
    const float4* __restrict__ bxLG, const float4* __restrict__ bxRG,
    const int* __restrict__ C1G, const int* __restrict__ C2G,
    float* __restrict__ out) {
  __shared__ SN S;
  int b = blockIdx.x, tid = threadIdx.x, ln = tid & 63, w = tid >> 6;
  float* ob = out + (size_t)b * NPROP * 9;

  // ---- finale (wave 0): AND keeps, rank, kth ties, write output rows ----
  if (w == 0) {
    int C1 = C1G[b];                 // 0 if select overflowed
    int before = 0;
    unsigned kth = 0;
    for (int wb = 0; wb * 64 < C1; ++wb) {
      u64 m = keepLG[b * WRD + wb] & keepRG[b * WRD + wb];
      int pos = wb * 64 + ln;
      bool bit = (m >> ln) & 1ull;
      int rank = before + (int)__popcll(m & ((1ull << ln) - 1ull));
      unsigned vA = svG[b * MAXC + pos];
      u64 selm = __ballot(bit && rank == DETS - 1);
      if (selm) kth = __shfl(vA, __ffsll(selm) - 1);
      bool qual = bit && (rank < DETS || vA == kth);
      if (qual) {
        int row = srowG[b * MAXC + pos];
        float4 L = bxLG[b * MAXC + pos], R = bxRG[b * MAXC + pos];
        float* orow = ob + row * 9;
        orow[0]=L.x; orow[1]=L.y; orow[2]=L.z; orow[3]=L.w;
        orow[4]=R.x; orow[5]=R.y; orow[6]=R.z; orow[7]=R.w;
        orow[8]=score_from_v(vA);
      }
      before += (int)__popcll(m);
    }
    if (ln == 0) {
      S.needFB = (before < DETS && C2G[b] > C1) ? 1 : 0;
      S.cnt = 0; S.prevCount = 0; S.done = 0; S.kthV = 0u;
    }
  }
  __syncthreads();
  if (!S.needFB) return;

  // ---- exact fallback (verified R6 path): full compact/sort/chunk NMS ----
  const float4* lp4 = (const float4*)lp;
  const float4* rp4 = (const float4*)rp;
  float4* ob4 = (float4*)ob;
  float4 z4 = make_float4(0.f, 0.f, 0.f, 0.f);
  for (int i = tid; i < NPROP * 9 / 4; i += 1024) ob4[i] = z4;
  for (int p = tid; p < NPROP; p += 1024) {
    unsigned v = v32G[b * NPROP + p];
    S.v32s[p] = v;
    bool cand = (v != 0xFFFFFFFFu);
    u64 mb = __ballot(cand);
    int lpos = (int)__popcll(mb & ((1ull << ln) - 1ull));
    int wb = 0;
    if (ln == 0 && mb) wb = atomicAdd(&S.cnt, (int)__popcll(mb));
    wb = __shfl(wb, 0);
    if (cand) S.keys[wb + lpos] = ((u64)v << 16) | (unsigned)p;
  }
  __syncthreads();
  int C2 = S.cnt;
  int CbEnd = (C2 + 63) & ~63;
  {
    int i0 = tid, i1 = tid + 1024;
    u64 k0 = (i0 < C2) ? S.keys[i0] : ~0ull;
    u64 k1 = (i1 < C2) ? S.keys[i1] : ~0ull;
    int r0 = 0, r1 = 0;
#pragma unroll 4
    for (int j = 0; j < C2; ++j) {
      u64 kj = S.keys[j];
      r0 += (kj < k0) ? 1 : 0;
      r1 += (kj < k1) ? 1 : 0;
    }
    if (i0 < C2) S.sidx[r0] = (unsigned short)(k0 & 0xFFFFull);
    if (i1 < C2) S.sidx[r1] = (unsigned short)(k1 & 0xFFFFull);
  }
  for (int i = C2 + tid; i < CbEnd; i += 1024) S.sidx[i] = 0;
  for (int wd = tid; wd < NPROP / 64; wd += 1024) {
    int b0 = wd << 6;
    u64 mf = 0ull;
    if (C2 >= b0 + 64) mf = ~0ull;
    else if (C2 > b0)  mf = (1ull << (C2 - b0)) - 1ull;
    S.keepbL[wd] = mf; S.keepbR[wd] = mf;
  }
  __syncthreads();
  {
    int lim = min(CbEnd, MAXC);
    for (int i = tid; i < lim; i += 1024) {
      if (i < C2) {
        int row = S.sidx[i];
        int grow = b * NPROP + row;
        int ci = ci16G[grow];
        float4 L = decode_side(reg, lp4, grow, ci, 0);
        float4 R = decode_side(reg, rp4, grow, ci, 1);
        S.bxL[i] = L; S.arL[i] = areaf(L);
        S.bxR[i] = R; S.arR[i] = areaf(R);
      } else {
        S.bxL[i] = z4; S.arL[i] = 1.0f;
        S.bxR[i] = z4; S.arR[i] = 1.0f;
      }
    }
  }
  __syncthreads();
  for (int base = 0; base < CbEnd; base += 64) {
    {
      int isR = (w >= 8);
      float4 cbx = get_sboxN(&S, reg, lp4, rp4, ci16G, b, base + ln, isR);
      float car = (base + ln < MAXC) ? (isR ? S.arR[base + ln] : S.arL[base + ln])
                                     : areaf(cbx);
      int w8 = w & 7;
#pragma unroll
      for (int k = 0; k < 8; ++k) {
        int row = w8 * 8 + k;
        float4 rbx;
        rbx.x = __shfl(cbx.x, row); rbx.y = __shfl(cbx.y, row);
        rbx.z = __shfl(cbx.z, row); rbx.w = __shfl(cbx.w, row);
        float rar = __shfl(car, row);
        bool bit = (ln > row) && iou_gt(rbx, rar, cbx, car);
        u64 bal = __ballot(bit);
        if (ln == 0) { if (isR) S.rowmR[row] = bal; else S.rowmL[row] = bal; }
      }
    }
    __syncthreads();
    if (tid < 128) {
      int isR = (tid >= 64);
      u64* km = isR ? S.keepbR : S.keepbL;
      u64* rm = isR ? S.rowmR  : S.rowmL;
      u64 a = km[base >> 6];
#pragma unroll
      for (int j = 0; j < 64; ++j)
        a &= ~((0ull - ((a >> j) & 1ull)) & rm[j]);
      if (ln == 0) {
        km[base >> 6] = a;
        if (isR) { S.aR = a; S.ccR = __popcll(a); }
        else     { S.aL = a; S.ccL = __popcll(a); }
      }
      if ((a >> ln) & 1ull) {
        int pos = __popcll(a & ((1ull << ln) - 1ull));
        float4 v = get_sboxN(&S, reg, lp4, rp4, ci16G, b, base + ln, isR);
        if (isR) { S.cbR[pos] = v; S.cbRa[pos] = areaf(v); }
        else     { S.cbL[pos] = v; S.cbLa[pos] = areaf(v); }
      }
    }
    __syncthreads();
    if (w == 0) {
      u64 m = S.aL & S.aR;
      int before = S.prevCount;
      bool bit = (m >> ln) & 1ull;
      int rank = before + (int)__popcll(m & ((1ull << ln) - 1ull));
      int row = S.sidx[base + ln];
      unsigned vA = S.v32s[row];
      u64 selm = __ballot(bit && rank == DETS - 1);
      unsigned keffV = S.kthV;
      if (selm) keffV = __shfl(vA, __ffsll(selm) - 1);
      bool qual = bit && (rank < DETS || vA == keffV);
      if (qual) {
        float4 L = get_sboxN(&S, reg, lp4, rp4, ci16G, b, base + ln, 0);
        float4 R = get_sboxN(&S, reg, lp4, rp4, ci16G, b, base + ln, 1);
        float s = score_from_v(vA);
        float* orow = ob + row * 9;
        orow[0]=L.x; orow[1]=L.y; orow[2]=L.z; orow[3]=L.w;
        orow[4]=R.x; orow[5]=R.y; orow[6]=R.z; orow[7]=R.w;
        orow[8]=s;
      }
      if (ln == 0) {
        if (selm) S.kthV = keffV;
        int nc = before + (int)__popcll(m);
        S.prevCount = nc;
        if (nc >= DETS) {
          int nxt = base + 64;
          bool cont = false;
          if (nxt < C2) cont = (S.v32s[S.sidx[nxt]] == keffV);
          if (!cont) S.done = 1;
        }
      }
    } else {
      int cL = S.ccL, cR = S.ccR;
      if ((cL | cR) != 0) {
        for (int p = base + 64 + (tid - 64); p < CbEnd; p += 960) {
          float4 mbL = get_sboxN(&S, reg, lp4, rp4, ci16G, b, p, 0);
          float al = (p < MAXC) ? S.arL[p] : areaf(mbL);
          bool supL = false;
          for (int q = 0; q < cL; ++q)
            supL = supL || iou_gt(mbL, al, S.cbL[q], S.cbLa[q]);
          if (supL) atomicAnd(&S.keepbL[p >> 6], ~(1ull << (p & 63)));
          float4 mbR = get_sboxN(&S, reg, lp4, rp4, ci16G, b, p, 1);
          float ar_ = (p < MAXC) ? S.arR[p] : areaf(mbR);
          bool supR = false;
          for (int q = 0; q < cR; ++q)
            supR = supR || iou_gt(mbR, ar_, S.cbR[q], S.cbRa[q]);
          if (supR) atomicAnd(&S.keepbR[p >> 6], ~(1ull << (p & 63)));
        }
      }
    }
    __syncthreads();
    if (S.done) break;
  }
}

// ---------------------------------------------------------------------------
extern "C" void kernel_launch(void* const* d_in, const int* in_sizes, int n_in,
                              void* d_out, int out_size, void* d_ws, size_t ws_size,
                              hipStream_t stream) {
  const float* logits = (const float*)d_in[0];   // [8192, 81]
  const float* reg    = (const float*)d_in[1];   // [8192, 648]
  const float* lprop  = (const float*)d_in[2];   // [8192, 4]
  const float* rprop  = (const float*)d_in[3];   // [8192, 4]
  float* out = (float*)d_out;                    // [4, 2048, 9]

  char* ws = (char*)d_ws;                        // ~125 KB used
  unsigned*       v32G   = (unsigned*)(ws + 0);          // 32 KB
  unsigned short* ci16G  = (unsigned short*)(ws + 32768);// 16 KB
  unsigned short* srowG  = (unsigned short*)(ws + 49152);// 4 KB
  unsigned*       svG    = (unsigned*)(ws + 53248);      // 8 KB
  float4*         bxLG   = (float4*)(ws + 61440);        // 32 KB
  float4*         bxRG   = (float4*)(ws + 94208);        // 32 KB
  u64*            keepLG = (u64*)(ws + 126976);          // 256 B
  u64*            keepRG = (u64*)(ws + 127232);          // 256 B
  int*            C1G    = (int*)(ws + 127488);
  int*            C2G    = (int*)(ws + 127504);
  int*            flagG  = (int*)(ws + 127520);

  score_kernel  <<<NIMG * NPROP / 4, 256,  0, stream>>>(logits, v32G, ci16G);
  select_kernel <<<NIMG,             1024, 0, stream>>>(v32G, srowG, svG, C1G, C2G, flagG);
  prep_kernel   <<<72,               256,  0, stream>>>(reg, lprop, rprop, ci16G, srowG,
                                                        C1G, flagG, out, bxLG, bxRG);
  build_kernel  <<<2 * NIMG,         1024, 0, stream>>>(bxLG, bxRG, C1G, flagG,
                                                        keepLG, keepRG);
  finale_fallback_kernel<<<NIMG,     1024, 0, stream>>>(reg, lprop, rprop, v32G, ci16G,
                                                        keepLG, keepRG, svG, srowG,
                                                        bxLG, bxRG, C1G, C2G, out);
}

// Round 10
// 123.260 us; speedup vs baseline: 1.3499x; 1.0511x over previous
//
#include <hip/hip_runtime.h>
#include <math.h>

// Problem constants (B=4, N=2048, C=81)
#define NPROP 2048
#define NIMG 4
#define NCLS 81
#define REGW 648          // C*8
#define SCORE_THRESH 0.05f
#define NMS_T 0.5f
#define DETS 100
#define XC 1023.0f        // IMG_W - 1
#define YC 799.0f         // IMG_H - 1
#define BBOX_CLIP 4.135166556742356f  // log(1000/16)
#define NBIN 8192         // 13-bit score-bin histogram (v >> 19)
#define SEL 320           // tranche target size
#define MAXC 512          // fast-path candidate cap
#define WRD 8             // MAXC/64 keep words
#define TRIP 2560         // padded triangular words: 64*(9+7+7+5+5+3+3+1)

typedef unsigned long long u64;

__device__ __forceinline__ float areaf(float4 v) {
  return fmaxf(v.z - v.x + 1.0f, 0.0f) * fmaxf(v.w - v.y + 1.0f, 0.0f);
}
__device__ __forceinline__ bool iou_gt(float4 a, float aa, float4 b, float ba) {
  float ix1 = fmaxf(a.x, b.x), iy1 = fmaxf(a.y, b.y);
  float ix2 = fminf(a.z, b.z), iy2 = fminf(a.w, b.w);
  float iw = fmaxf(ix2 - ix1 + 1.0f, 0.0f);
  float ih = fmaxf(iy2 - iy1 + 1.0f, 0.0f);
  float inter = iw * ih;
  return inter > NMS_T * fmaxf(aa + ba - inter, 1e-6f);
}
__device__ __forceinline__ float score_from_v(unsigned v) {
  unsigned uu = ~v;
  unsigned bits = (uu & 0x80000000u) ? (uu & 0x7fffffffu) : ~uu;
  return __uint_as_float(bits);
}
__device__ __forceinline__ float4 decode_side(const float* __restrict__ reg,
                                              const float4* __restrict__ props,
                                              int grow, int ci, int isR) {
  const float* r = reg + (size_t)grow * REGW + ci * 8 + isR * 4;
  float4 P = props[grow];
  float w  = P.z - P.x + 1.0f;
  float h  = P.w - P.y + 1.0f;
  float cx = P.x + 0.5f * w;
  float cy = P.y + 0.5f * h;
  float dx = r[0] / 10.0f;
  float dy = r[1] / 10.0f;
  float dw = fminf(r[2] / 5.0f, BBOX_CLIP);
  float dh = fminf(r[3] / 5.0f, BBOX_CLIP);
  float pcx = dx * w + cx;
  float pcy = dy * h + cy;
  float pw = expf(dw) * w;
  float ph = expf(dh) * h;
  float4 o;
  o.x = fminf(fmaxf(pcx - 0.5f * pw, 0.0f), XC);
  o.y = fminf(fmaxf(pcy - 0.5f * ph, 0.0f), YC);
  o.z = fminf(fmaxf(pcx + 0.5f * pw - 1.0f, 0.0f), XC);
  o.w = fminf(fmaxf(pcy + 0.5f * ph - 1.0f, 0.0f), YC);
  return o;
}

// ---------------------------------------------------------------------------
// K1: wide per-row softmax-argmax -> v32 + ci16; first 72 blocks also zero out.
// ---------------------------------------------------------------------------
__global__ __launch_bounds__(256) void score_kernel(
    const float* __restrict__ logits,
    unsigned* __restrict__ v32G, unsigned short* __restrict__ ci16G,
    float* __restrict__ out) {
  int row  = blockIdx.x * 4 + (threadIdx.x >> 6);
  int lane = threadIdx.x & 63;
  if (blockIdx.x < 72) {                // zero output: 72*256 = 18432 float4s
    int g = blockIdx.x * 256 + threadIdx.x;
    ((float4*)out)[g] = make_float4(0.f, 0.f, 0.f, 0.f);
  }
  const float* lr = logits + (size_t)row * NCLS;
  float a = lr[lane];
  float b = (lane < NCLS - 64) ? lr[lane + 64] : -INFINITY;
  float v; int ci;
  if (b > a) { v = b; ci = lane + 64; } else { v = a; ci = lane; }
  for (int o = 32; o; o >>= 1) {        // wave argmax, min-index ties
    float ov = __shfl_xor(v, o);
    int   oc = __shfl_xor(ci, o);
    if (ov > v || (ov == v && oc < ci)) { v = ov; ci = oc; }
  }
  float e = expf(a - v) + ((lane < NCLS - 64) ? expf(b - v) : 0.0f);
  for (int o = 32; o; o >>= 1) e += __shfl_xor(e, o);
  if (lane == 0) {
    float score = 1.0f / e;             // softmax at argmax (numerator exp(0))
    unsigned vv = 0xFFFFFFFFu;
    if (ci >= 1 && score > SCORE_THRESH) {
      unsigned uu = __float_as_uint(score);
      uu = (uu & 0x80000000u) ? ~uu : (uu | 0x80000000u);
      vv = ~uu;                         // ascending vv == descending score
    }
    v32G[row]  = vv;
    ci16G[row] = (unsigned short)ci;
  }
}

// ---------------------------------------------------------------------------
// K2 (8 blocks = image x side, 1024 thr): fused select + decode + matrix +
// greedy. Select (hist threshold, compact, rank-sort) runs redundantly on
// both side-blocks of an image — identical deterministic results, duplicate
// global writes are benign. Decode covers only this block's side. Matrix /
// greedy are the R9-verified latency-free versions.
// ---------------------------------------------------------------------------
__global__ __launch_bounds__(1024) void nms8_kernel(
    const unsigned* __restrict__ v32G, const unsigned short* __restrict__ ci16G,
    const float* __restrict__ reg, const float* __restrict__ lp,
    const float* __restrict__ rp,
    unsigned short* __restrict__ srowG, unsigned* __restrict__ svG,
    float4* __restrict__ bxLG, float4* __restrict__ bxRG,
    u64* __restrict__ keepLG, u64* __restrict__ keepRG,
    int* __restrict__ C1G, int* __restrict__ C2G, int* __restrict__ flagG) {
  __shared__ int hist[NBIN];            // 32 KB
  __shared__ u64 keys[MAXC];            // 4 KB
  __shared__ unsigned short ssort[MAXC];// 1 KB sorted pos -> row
  __shared__ float4 bx[MAXC];           // 8 KB decoded boxes (this side)
  __shared__ u64 mat[TRIP];             // 20 KB triangular bit matrix
  __shared__ int wsum[16];
  __shared__ int Ts, cnts, ovf;
  int b = blockIdx.x >> 1, side = blockIdx.x & 1;
  int tid = threadIdx.x, ln = tid & 63, w = tid >> 6;
  const unsigned* v32 = v32G + b * NPROP;
  if (tid == 0) { Ts = NBIN - 1; cnts = 0; ovf = 0; }
  for (int i = tid; i < NBIN; i += 1024) hist[i] = 0;
  __syncthreads();
  for (int p = tid; p < NPROP; p += 1024) {
    unsigned v = v32[p];
    if (v != 0xFFFFFFFFu) atomicAdd(&hist[v >> 19], 1);
  }
  __syncthreads();
  {  // scan 8192 bins (8/thread) -> threshold bin Ts (cum >= SEL), total
    int base = tid * 8;
    int c[8]; int acc = 0;
#pragma unroll
    for (int k = 0; k < 8; ++k) { acc += hist[base + k]; c[k] = acc; }
    int tot = acc, v = tot;
#pragma unroll
    for (int o = 1; o < 64; o <<= 1) { int n = __shfl_up(v, o); if (ln >= o) v += n; }
    if (ln == 63) wsum[w] = v;
    __syncthreads();
    if (tid < 16) {
      int x = wsum[tid];
#pragma unroll
      for (int o = 1; o < 16; o <<= 1) { int n = __shfl_up(x, o); if (tid >= o) x += n; }
      wsum[tid] = x;
    }
    __syncthreads();
    int incl = ((w > 0) ? wsum[w - 1] : 0) + v;
    int off = incl - tot;
    int prev = off;
#pragma unroll
    for (int k = 0; k < 8; ++k) {
      int cur = off + c[k];
      if (cur >= SEL && prev < SEL) Ts = base + k;
      prev = cur;
    }
  }
  __syncthreads();
  int T = Ts, nvTot = wsum[15];
  for (int p = tid; p < NPROP; p += 1024) {   // compact bin <= T
    unsigned v = v32[p];
    bool cand = (v != 0xFFFFFFFFu) && ((int)(v >> 19) <= T);
    u64 mb = __ballot(cand);
    int lpos = (int)__popcll(mb & ((1ull << ln) - 1ull));
    int wb = 0;
    if (ln == 0 && mb) wb = atomicAdd(&cnts, (int)__popcll(mb));
    wb = __shfl(wb, 0);
    if (cand) {
      int dst = wb + lpos;
      if (dst < MAXC) keys[dst] = ((u64)v << 16) | (unsigned)p;
      else ovf = 1;
    }
  }
  __syncthreads();
  int C1 = cnts;
  if (C1 > MAXC || ovf) {    // overflow -> exact fallback path
    if (tid == 0) { flagG[b] = 1; C1G[b] = 0; C2G[b] = nvTot; }
    return;
  }
  if (tid == 0) { flagG[b] = 0; C1G[b] = C1; C2G[b] = nvTot; }
  if (tid < 256) {   // rank-sort, 2 keys/thread (4 waves issue the LDS loop)
    int i0 = tid, i1 = tid + 256;
    u64 k0 = (i0 < C1) ? keys[i0] : ~0ull;
    u64 k1 = (i1 < C1) ? keys[i1] : ~0ull;
    int r0 = 0, r1 = 0;
#pragma unroll 4
    for (int j = 0; j < C1; ++j) {
      u64 kj = keys[j];
      r0 += (kj < k0) ? 1 : 0;
      r1 += (kj < k1) ? 1 : 0;
    }
    if (i0 < C1) {
      unsigned short rw = (unsigned short)(k0 & 0xFFFFull);
      ssort[r0] = rw;
      srowG[b * MAXC + r0] = rw;                  // duplicate across sides: benign
      svG[b * MAXC + r0]   = (unsigned)(k0 >> 16);
    }
    if (i1 < C1) {
      unsigned short rw = (unsigned short)(k1 & 0xFFFFull);
      ssort[r1] = rw;
      srowG[b * MAXC + r1] = rw;
      svG[b * MAXC + r1]   = (unsigned)(k1 >> 16);
    }
  }
  __syncthreads();

  // ---- decode this side's boxes for sorted positions < MAXC ----
  int WRDu = (C1 + 63) >> 6;
  if (tid < MAXC) {
    float4 B = make_float4(0.f, 0.f, 0.f, 0.f);
    if (tid < C1) {
      int row  = ssort[tid];
      int grow = b * NPROP + row;
      int ci   = ci16G[grow];
      B = decode_side(reg, (const float4*)(side ? rp : lp), grow, ci, side);
      (side ? bxRG : bxLG)[b * MAXC + tid] = B;   // for finale output rows
    }
    bx[tid] = B;
  }
  __syncthreads();

  // ---- matrix build: wave w -> row-block rb=w&7, column parity part=w>>3 ----
  {
    int rb = w & 7, part = w >> 3;
    int r = rb * 64 + ln;
    float4 rbx = bx[r];
    float  rar = areaf(rbx);
    int tb = 0;
    for (int k = 0; k < rb; ++k) tb += ((8 - k) | 1);
    int Sw = (8 - rb) | 1;
    u64* myrow = &mat[tb * 64 + ln * Sw];
    for (int cw = rb + part; cw < WRDu; cw += 2) {
      u64 m = 0;
      const float4* cp = &bx[cw * 64];
#pragma unroll 8
      for (int c = 0; c < 64; ++c) {
        float4 cb = cp[c];             // same-address broadcast ds_read_b128
        float car = areaf(cb);
        if (iou_gt(rbx, rar, cb, car)) m |= (1ull << c);
      }
      if (cw == rb) m &= ~((2ull << ln) - 1ull);   // keep only col > r
      myrow[cw - rb] = m;
    }
  }
  __syncthreads();

  // ---- greedy: wave 0, all lanes redundant, zero barriers (R9-verified) ----
  if (w == 0) {
    u64 A[WRD];
#pragma unroll
    for (int t = 0; t < WRD; ++t) {
      int b0 = t * 64;
      A[t] = (C1 >= b0 + 64) ? ~0ull : (C1 > b0 ? ((1ull << (C1 - b0)) - 1ull) : 0ull);
    }
    int tbase = 0;
#pragma unroll
    for (int wb = 0; wb < WRD; ++wb) {
      if (wb * 64 < C1) {
        const int Sw = (8 - wb) | 1;
        const u64* rowp = &mat[tbase];
        u64 aw = A[wb];
        // diag-only serial sweep; loads batched 16-at-a-time into registers
#pragma unroll
        for (int g = 0; g < 4; ++g) {
          u64 d[16];
#pragma unroll
          for (int k = 0; k < 16; ++k) d[k] = rowp[(g * 16 + k) * Sw];
#pragma unroll
          for (int k = 0; k < 16; ++k) {
            u64 msk = 0ull - ((aw >> (g * 16 + k)) & 1ull);
            aw &= ~(msk & d[k]);
          }
        }
        A[wb] = aw;
        // off-diagonal suppression: lane-parallel, shfl OR-reduce
        bool alive = (aw >> ln) & 1ull;
#pragma unroll
        for (int t = wb + 1; t < WRD; ++t) {
          if (t * 64 < C1) {
            u64 x = alive ? rowp[ln * Sw + (t - wb)] : 0ull;
#pragma unroll
            for (int o = 1; o < 64; o <<= 1)
              x |= __shfl_xor((unsigned long long)x, o);
            A[t] &= ~x;
          }
        }
      }
      tbase += 64 * ((8 - wb) | 1);
    }
    if (ln == 0) {
      u64* kG = (side ? keepRG : keepLG) + b * WRD;
#pragma unroll
      for (int t = 0; t < WRD; ++t)
        if (t * 64 < C1) kG[t] = A[t];
    }
  }
}

// ---------------------------------------------------------------------------
// K3: finale (wave 0) + dormant exact fallback in one kernel (4 blocks).
// ---------------------------------------------------------------------------
struct SN {
  u64 keys[NPROP];
  unsigned short sidx[NPROP];
  unsigned v32s[NPROP];
  float4 bxL[MAXC], bxR[MAXC];
  float  arL[MAXC], arR[MAXC];
  u64 keepbL[NPROP / 64], keepbR[NPROP / 64];
  u64 rowmL[64], rowmR[64];
  float4 cbL[64], cbR[64];
  float  cbLa[64], cbRa[64];
  u64 aL, aR;
  int cnt, prevCount, done, ccL, ccR, needFB;
  unsigned kthV;
};

__device__ __forceinline__ float4 get_sboxN(SN* S, const float* reg,
                                            const float4* lp4, const float4* rp4,
                                            const unsigned short* ci16G,
                                            int b, int pos, int isR) {
  if (pos < MAXC) return isR ? S->bxR[pos] : S->bxL[pos];
  int row = S->sidx[pos];
  int grow = b * NPROP + row;
  return decode_side(reg, isR ? rp4 : lp4, grow, ci16G[grow], isR);
}

__global__ __launch_bounds__(1024) void finale_fallback_kernel(
    const float* __restrict__ reg, const float* __restrict__ lp,
    const float* __restrict__ rp, const unsigned* __restrict__ v32G,
    const unsigned short* __restrict__ ci16G,
    const u64* __restrict__ keepLG, const u64* __restrict__ keepRG,
    const unsigned* __restrict__ svG, const unsigned short* __restrict__ srowG,
    const float4* __restrict__ bxLG, const float4* __restrict__ bxRG,
    const int* __restrict__ C1G, const int* __restrict__ C2G,
    float* __restrict__ out) {
  __shared__ SN S;
  int b = blockIdx.x, tid = threadIdx.x, ln = tid & 63, w = tid >> 6;
  float* ob = out + (size_t)b * NPROP * 9;

  // ---- finale (wave 0): AND keeps, rank, kth ties, write output rows ----
  if (w == 0) {
    int C1 = C1G[b];                 // 0 if select overflowed
    int before = 0;
    unsigned kth = 0;
    for (int wb = 0; wb * 64 < C1; ++wb) {
      u64 m = keepLG[b * WRD + wb] & keepRG[b * WRD + wb];
      int pos = wb * 64 + ln;
      bool bit = (m >> ln) & 1ull;
      int rank = before + (int)__popcll(m & ((1ull << ln) - 1ull));
      unsigned vA = svG[b * MAXC + pos];
      u64 selm = __ballot(bit && rank == DETS - 1);
      if (selm) kth = __shfl(vA, __ffsll(selm) - 1);
      bool qual = bit && (rank < DETS || vA == kth);
      if (qual) {
        int row = srowG[b * MAXC + pos];
        float4 L = bxLG[b * MAXC + pos], R = bxRG[b * MAXC + pos];
        float* orow = ob + row * 9;
        orow[0]=L.x; orow[1]=L.y; orow[2]=L.z; orow[3]=L.w;
        orow[4]=R.x; orow[5]=R.y; orow[6]=R.z; orow[7]=R.w;
        orow[8]=score_from_v(vA);
      }
      before += (int)__popcll(m);
    }
    if (ln == 0) {
      S.needFB = (before < DETS && C2G[b] > C1) ? 1 : 0;
      S.cnt = 0; S.prevCount = 0; S.done = 0; S.kthV = 0u;
    }
  }
  __syncthreads();
  if (!S.needFB) return;

  // ---- exact fallback (verified R6 path): full compact/sort/chunk NMS ----
  const float4* lp4 = (const float4*)lp;
  const float4* rp4 = (const float4*)rp;
  float4* ob4 = (float4*)ob;
  float4 z4 = make_float4(0.f, 0.f, 0.f, 0.f);
  for (int i = tid; i < NPROP * 9 / 4; i += 1024) ob4[i] = z4;
  for (int p = tid; p < NPROP; p += 1024) {
    unsigned v = v32G[b * NPROP + p];
    S.v32s[p] = v;
    bool cand = (v != 0xFFFFFFFFu);
    u64 mb = __ballot(cand);
    int lpos = (int)__popcll(mb & ((1ull << ln) - 1ull));
    int wb = 0;
    if (ln == 0 && mb) wb = atomicAdd(&S.cnt, (int)__popcll(mb));
    wb = __shfl(wb, 0);
    if (cand) S.keys[wb + lpos] = ((u64)v << 16) | (unsigned)p;
  }
  __syncthreads();
  int C2 = S.cnt;
  int CbEnd = (C2 + 63) & ~63;
  {
    int i0 = tid, i1 = tid + 1024;
    u64 k0 = (i0 < C2) ? S.keys[i0] : ~0ull;
    u64 k1 = (i1 < C2) ? S.keys[i1] : ~0ull;
    int r0 = 0, r1 = 0;
#pragma unroll 4
    for (int j = 0; j < C2; ++j) {
      u64 kj = S.keys[j];
      r0 += (kj < k0) ? 1 : 0;
      r1 += (kj < k1) ? 1 : 0;
    }
    if (i0 < C2) S.sidx[r0] = (unsigned short)(k0 & 0xFFFFull);
    if (i1 < C2) S.sidx[r1] = (unsigned short)(k1 & 0xFFFFull);
  }
  for (int i = C2 + tid; i < CbEnd; i += 1024) S.sidx[i] = 0;
  for (int wd = tid; wd < NPROP / 64; wd += 1024) {
    int b0 = wd << 6;
    u64 mf = 0ull;
    if (C2 >= b0 + 64) mf = ~0ull;
    else if (C2 > b0)  mf = (1ull << (C2 - b0)) - 1ull;
    S.keepbL[wd] = mf; S.keepbR[wd] = mf;
  }
  __syncthreads();
  {
    int lim = min(CbEnd, MAXC);
    for (int i = tid; i < lim; i += 1024) {
      if (i < C2) {
        int row = S.sidx[i];
        int grow = b * NPROP + row;
        int ci = ci16G[grow];
        float4 L = decode_side(reg, lp4, grow, ci, 0);
        float4 R = decode_side(reg, lp4 == rp4 ? lp4 : rp4, grow, ci, 1);
        S.bxL[i] = L; S.arL[i] = areaf(L);
        S.bxR[i] = R; S.arR[i] = areaf(R);
      } else {
        S.bxL[i] = z4; S.arL[i] = 1.0f;
        S.bxR[i] = z4; S.arR[i] = 1.0f;
      }
    }
  }
  __syncthreads();
  for (int base = 0; base < CbEnd; base += 64) {
    {
      int isR = (w >= 8);
      float4 cbx = get_sboxN(&S, reg, lp4, rp4, ci16G, b, base + ln, isR);
      float car = (base + ln < MAXC) ? (isR ? S.arR[base + ln] : S.arL[base + ln])
                                     : areaf(cbx);
      int w8 = w & 7;
#pragma unroll
      for (int k = 0; k < 8; ++k) {
        int row = w8 * 8 + k;
        float4 rbx;
        rbx.x = __shfl(cbx.x, row); rbx.y = __shfl(cbx.y, row);
        rbx.z = __shfl(cbx.z, row); rbx.w = __shfl(cbx.w, row);
        float rar = __shfl(car, row);
        bool bit = (ln > row) && iou_gt(rbx, rar, cbx, car);
        u64 bal = __ballot(bit);
        if (ln == 0) { if (isR) S.rowmR[row] = bal; else S.rowmL[row] = bal; }
      }
    }
    __syncthreads();
    if (tid < 128) {
      int isR = (tid >= 64);
      u64* km = isR ? S.keepbR : S.keepbL;
      u64* rm = isR ? S.rowmR  : S.rowmL;
      u64 a = km[base >> 6];
#pragma unroll
      for (int j = 0; j < 64; ++j)
        a &= ~((0ull - ((a >> j) & 1ull)) & rm[j]);
      if (ln == 0) {
        km[base >> 6] = a;
        if (isR) { S.aR = a; S.ccR = __popcll(a); }
        else     { S.aL = a; S.ccL = __popcll(a); }
      }
      if ((a >> ln) & 1ull) {
        int pos = __popcll(a & ((1ull << ln) - 1ull));
        float4 v = get_sboxN(&S, reg, lp4, rp4, ci16G, b, base + ln, isR);
        if (isR) { S.cbR[pos] = v; S.cbRa[pos] = areaf(v); }
        else     { S.cbL[pos] = v; S.cbLa[pos] = areaf(v); }
      }
    }
    __syncthreads();
    if (w == 0) {
      u64 m = S.aL & S.aR;
      int before = S.prevCount;
      bool bit = (m >> ln) & 1ull;
      int rank = before + (int)__popcll(m & ((1ull << ln) - 1ull));
      int row = S.sidx[base + ln];
      unsigned vA = S.v32s[row];
      u64 selm = __ballot(bit && rank == DETS - 1);
      unsigned keffV = S.kthV;
      if (selm) keffV = __shfl(vA, __ffsll(selm) - 1);
      bool qual = bit && (rank < DETS || vA == keffV);
      if (qual) {
        float4 L = get_sboxN(&S, reg, lp4, rp4, ci16G, b, base + ln, 0);
        float4 R = get_sboxN(&S, reg, lp4, rp4, ci16G, b, base + ln, 1);
        float s = score_from_v(vA);
        float* orow = ob + row * 9;
        orow[0]=L.x; orow[1]=L.y; orow[2]=L.z; orow[3]=L.w;
        orow[4]=R.x; orow[5]=R.y; orow[6]=R.z; orow[7]=R.w;
        orow[8]=s;
      }
      if (ln == 0) {
        if (selm) S.kthV = keffV;
        int nc = before + (int)__popcll(m);
        S.prevCount = nc;
        if (nc >= DETS) {
          int nxt = base + 64;
          bool cont = false;
          if (nxt < C2) cont = (S.v32s[S.sidx[nxt]] == keffV);
          if (!cont) S.done = 1;
        }
      }
    } else {
      int cL = S.ccL, cR = S.ccR;
      if ((cL | cR) != 0) {
        for (int p = base + 64 + (tid - 64); p < CbEnd; p += 960) {
          float4 mbL = get_sboxN(&S, reg, lp4, rp4, ci16G, b, p, 0);
          float al = (p < MAXC) ? S.arL[p] : areaf(mbL);
          bool supL = false;
          for (int q = 0; q < cL; ++q)
            supL = supL || iou_gt(mbL, al, S.cbL[q], S.cbLa[q]);
          if (supL) atomicAnd(&S.keepbL[p >> 6], ~(1ull << (p & 63)));
          float4 mbR = get_sboxN(&S, reg, lp4, rp4, ci16G, b, p, 1);
          float ar_ = (p < MAXC) ? S.arR[p] : areaf(mbR);
          bool supR = false;
          for (int q = 0; q < cR; ++q)
            supR = supR || iou_gt(mbR, ar_, S.cbR[q], S.cbRa[q]);
          if (supR) atomicAnd(&S.keepbR[p >> 6], ~(1ull << (p & 63)));
        }
      }
    }
    __syncthreads();
    if (S.done) break;
  }
}

// ---------------------------------------------------------------------------
extern "C" void kernel_launch(void* const* d_in, const int* in_sizes, int n_in,
                              void* d_out, int out_size, void* d_ws, size_t ws_size,
                              hipStream_t stream) {
  const float* logits = (const float*)d_in[0];   // [8192, 81]
  const float* reg    = (const float*)d_in[1];   // [8192, 648]
  const float* lprop  = (const float*)d_in[2];   // [8192, 4]
  const float* rprop  = (const float*)d_in[3];   // [8192, 4]
  float* out = (float*)d_out;                    // [4, 2048, 9]

  char* ws = (char*)d_ws;                        // ~125 KB used
  unsigned*       v32G   = (unsigned*)(ws + 0);          // 32 KB
  unsigned short* ci16G  = (unsigned short*)(ws + 32768);// 16 KB
  unsigned short* srowG  = (unsigned short*)(ws + 49152);// 4 KB
  unsigned*       svG    = (unsigned*)(ws + 53248);      // 8 KB
  float4*         bxLG   = (float4*)(ws + 61440);        // 32 KB
  float4*         bxRG   = (float4*)(ws + 94208);        // 32 KB
  u64*            keepLG = (u64*)(ws + 126976);          // 256 B
  u64*            keepRG = (u64*)(ws + 127232);          // 256 B
  int*            C1G    = (int*)(ws + 127488);
  int*            C2G    = (int*)(ws + 127504);
  int*            flagG  = (int*)(ws + 127520);

  score_kernel<<<NIMG * NPROP / 4, 256,  0, stream>>>(logits, v32G, ci16G, out);
  nms8_kernel <<<2 * NIMG,         1024, 0, stream>>>(v32G, ci16G, reg, lprop, rprop,
                                                      srowG, svG, bxLG, bxRG,
                                                      keepLG, keepRG, C1G, C2G, flagG);
  finale_fallback_kernel<<<NIMG,   1024, 0, stream>>>(reg, lprop, rprop, v32G, ci16G,
                                                      keepLG, keepRG, svG, srowG,
                                                      bxLG, bxRG, C1G, C2G, out);
}